// Round 8
// baseline (3754.361 us; speedup 1.0000x reference)
//
#include <hip/hip_runtime.h>

#define NN 100000
#define NE 1600000
#define HF 128
#define INF 16
#define NLAYERS 19

static inline int idiv(int a, int b) { return (a + b - 1) / b; }

__device__ __forceinline__ float leaky(float v) { return (v >= 0.f) ? v : 0.01f * v; }

// ---------------- preprocessing ----------------

__global__ __launch_bounds__(256) void k_deg1(const int* __restrict__ idx, int* __restrict__ deg, int e) {
  int i = (blockIdx.x * 256 + threadIdx.x) * 4;
  if (i + 4 <= e) {
    int4 v = *reinterpret_cast<const int4*>(idx + i);
    atomicAdd(&deg[v.x], 1);
    atomicAdd(&deg[v.y], 1);
    atomicAdd(&deg[v.z], 1);
    atomicAdd(&deg[v.w], 1);
  } else {
    for (; i < e; ++i) atomicAdd(&deg[idx[i]], 1);
  }
}

__global__ __launch_bounds__(256) void k_norms(const int* __restrict__ dout, const int* __restrict__ din,
                                               float* __restrict__ iso, float* __restrict__ isi, int n) {
  int i = blockIdx.x * 256 + threadIdx.x;
  if (i < n) {
    iso[i] = rsqrtf((float)(dout[i] > 1 ? dout[i] : 1));
    isi[i] = rsqrtf((float)(din[i] > 1 ? din[i] : 1));
  }
}

// single-block exclusive scan of counts -> row_ptr
__global__ __launch_bounds__(1024) void k_scan(const int* __restrict__ cnt, int* __restrict__ rp, int n) {
  __shared__ int wsum[16];
  const int tid = threadIdx.x;
  const int lane = tid & 63;
  const int wid = tid >> 6;
  int carry = 0;
  for (int base = 0; base < n; base += 1024) {
    int i = base + tid;
    int v = (i < n) ? cnt[i] : 0;
    int x = v;
#pragma unroll
    for (int off = 1; off < 64; off <<= 1) {
      int t = __shfl_up(x, off, 64);
      if (lane >= off) x += t;
    }
    if (lane == 63) wsum[wid] = x;
    __syncthreads();
    if (wid == 0) {
      int s = (lane < 16) ? wsum[lane] : 0;
#pragma unroll
      for (int off = 1; off < 16; off <<= 1) {
        int t = __shfl_up(s, off, 64);
        if (lane >= off) s += t;
      }
      if (lane < 16) wsum[lane] = s;
    }
    __syncthreads();
    int woff = (wid > 0) ? wsum[wid - 1] : 0;
    if (i < n) rp[i] = carry + woff + x - v;
    carry += wsum[15];
    __syncthreads();
  }
  if (tid == 0) rp[n] = carry;
}

// build packed CSR: cv[pos] = {col, bits(val)}
__global__ __launch_bounds__(256) void k_build(const int* __restrict__ src, const int* __restrict__ dst,
                                               const float* __restrict__ ew, const float* __restrict__ iso,
                                               const float* __restrict__ isi, const int* __restrict__ rp,
                                               int* __restrict__ cursor, int2* __restrict__ cv, int e) {
  int i = blockIdx.x * 256 + threadIdx.x;
  if (i < e) {
    int s = src[i], d = dst[i];
    int pos = rp[d] + atomicAdd(&cursor[d], 1);
    float v = ew[i] * iso[s] * isi[d];
    cv[pos] = make_int2(s, __float_as_int(v));
  }
}

// ---------------- layer 1 (16 feats) ----------------

__global__ __launch_bounds__(256) void k_spmm16(const float* __restrict__ x, const int* __restrict__ rp,
                                                const int2* __restrict__ cv, float* __restrict__ agg16, int n) {
  int t = blockIdx.x * 256 + threadIdx.x;
  int node = t >> 4, f = t & 15;
  if (node >= n) return;
  int e = rp[node], end = rp[node + 1];
  float a = 0.f;
  for (; e + 4 <= end; e += 4) {
    int2 q0 = cv[e], q1 = cv[e + 1], q2 = cv[e + 2], q3 = cv[e + 3];
    float x0 = x[(size_t)q0.x * INF + f];
    float x1 = x[(size_t)q1.x * INF + f];
    float x2 = x[(size_t)q2.x * INF + f];
    float x3 = x[(size_t)q3.x * INF + f];
    a = fmaf(__int_as_float(q0.y), x0, a);
    a = fmaf(__int_as_float(q1.y), x1, a);
    a = fmaf(__int_as_float(q2.y), x2, a);
    a = fmaf(__int_as_float(q3.y), x3, a);
  }
  for (; e < end; ++e) {
    int2 q = cv[e];
    a = fmaf(__int_as_float(q.y), x[(size_t)q.x * INF + f], a);
  }
  agg16[(size_t)node * INF + f] = a;
}

__global__ __launch_bounds__(256) void k_gemm16(const float* __restrict__ agg16, const float* __restrict__ W1,
                                                const float* __restrict__ b1, float* __restrict__ h, int n) {
  __shared__ float W1s[INF * HF];
  int tid = threadIdx.x;
  {
    float4* d4 = reinterpret_cast<float4*>(W1s);
    const float4* s4 = reinterpret_cast<const float4*>(W1);
    d4[tid] = s4[tid];
    d4[tid + 256] = s4[tid + 256];
  }
  __syncthreads();
  int t = blockIdx.x * 256 + tid;
  int node = t >> 7, c = t & 127;
  if (node >= n) return;
  const float* ar = agg16 + (size_t)node * INF;
  float4 a0 = *reinterpret_cast<const float4*>(ar);
  float4 a1 = *reinterpret_cast<const float4*>(ar + 4);
  float4 a2 = *reinterpret_cast<const float4*>(ar + 8);
  float4 a3 = *reinterpret_cast<const float4*>(ar + 12);
  float av[16] = {a0.x, a0.y, a0.z, a0.w, a1.x, a1.y, a1.z, a1.w,
                  a2.x, a2.y, a2.z, a2.w, a3.x, a3.y, a3.z, a3.w};
  float a = b1[c];
#pragma unroll
  for (int f = 0; f < INF; ++f) a = fmaf(av[f], W1s[f * HF + c], a);
  h[(size_t)t] = leaky(a);
}

// ---------------- hidden layers ----------------

// wave-per-node, float2 per lane, 8-deep gather pipeline (at fabric BW ceiling).
// Node-range split [n0, n1) so per-dispatch duration drops below k_gemm's,
// unmasking k_gemm in rocprof top-5 (instrumentation; spmm itself is closed).
__global__ __launch_bounds__(256) void k_spmm(const float* __restrict__ h, const int* __restrict__ rp,
                                              const int2* __restrict__ cv, float* __restrict__ agg,
                                              int n0, int n1) {
  const int lane = threadIdx.x & 63;
  const int node = __builtin_amdgcn_readfirstlane(n0 + blockIdx.x * 4 + (threadIdx.x >> 6));
  if (node >= n1) return;
  const int beg = rp[node], end = rp[node + 1];
  const size_t fo = (size_t)(lane << 1);
  float ax = 0.f, ay = 0.f;
  int e = beg;
  for (; e + 8 <= end; e += 8) {
    int2 q0 = cv[e + 0], q1 = cv[e + 1], q2 = cv[e + 2], q3 = cv[e + 3];
    int2 q4 = cv[e + 4], q5 = cv[e + 5], q6 = cv[e + 6], q7 = cv[e + 7];
    float2 x0 = *reinterpret_cast<const float2*>(h + (size_t)q0.x * HF + fo);
    float2 x1 = *reinterpret_cast<const float2*>(h + (size_t)q1.x * HF + fo);
    float2 x2 = *reinterpret_cast<const float2*>(h + (size_t)q2.x * HF + fo);
    float2 x3 = *reinterpret_cast<const float2*>(h + (size_t)q3.x * HF + fo);
    float2 x4 = *reinterpret_cast<const float2*>(h + (size_t)q4.x * HF + fo);
    float2 x5 = *reinterpret_cast<const float2*>(h + (size_t)q5.x * HF + fo);
    float2 x6 = *reinterpret_cast<const float2*>(h + (size_t)q6.x * HF + fo);
    float2 x7 = *reinterpret_cast<const float2*>(h + (size_t)q7.x * HF + fo);
    ax = fmaf(__int_as_float(q0.y), x0.x, ax); ay = fmaf(__int_as_float(q0.y), x0.y, ay);
    ax = fmaf(__int_as_float(q1.y), x1.x, ax); ay = fmaf(__int_as_float(q1.y), x1.y, ay);
    ax = fmaf(__int_as_float(q2.y), x2.x, ax); ay = fmaf(__int_as_float(q2.y), x2.y, ay);
    ax = fmaf(__int_as_float(q3.y), x3.x, ax); ay = fmaf(__int_as_float(q3.y), x3.y, ay);
    ax = fmaf(__int_as_float(q4.y), x4.x, ax); ay = fmaf(__int_as_float(q4.y), x4.y, ay);
    ax = fmaf(__int_as_float(q5.y), x5.x, ax); ay = fmaf(__int_as_float(q5.y), x5.y, ay);
    ax = fmaf(__int_as_float(q6.y), x6.x, ax); ay = fmaf(__int_as_float(q6.y), x6.y, ay);
    ax = fmaf(__int_as_float(q7.y), x7.x, ax); ay = fmaf(__int_as_float(q7.y), x7.y, ay);
  }
  if (e + 4 <= end) {
    int2 q0 = cv[e + 0], q1 = cv[e + 1], q2 = cv[e + 2], q3 = cv[e + 3];
    float2 x0 = *reinterpret_cast<const float2*>(h + (size_t)q0.x * HF + fo);
    float2 x1 = *reinterpret_cast<const float2*>(h + (size_t)q1.x * HF + fo);
    float2 x2 = *reinterpret_cast<const float2*>(h + (size_t)q2.x * HF + fo);
    float2 x3 = *reinterpret_cast<const float2*>(h + (size_t)q3.x * HF + fo);
    ax = fmaf(__int_as_float(q0.y), x0.x, ax); ay = fmaf(__int_as_float(q0.y), x0.y, ay);
    ax = fmaf(__int_as_float(q1.y), x1.x, ax); ay = fmaf(__int_as_float(q1.y), x1.y, ay);
    ax = fmaf(__int_as_float(q2.y), x2.x, ax); ay = fmaf(__int_as_float(q2.y), x2.y, ay);
    ax = fmaf(__int_as_float(q3.y), x3.x, ax); ay = fmaf(__int_as_float(q3.y), x3.y, ay);
    e += 4;
  }
  if (e + 2 <= end) {
    int2 q0 = cv[e + 0], q1 = cv[e + 1];
    float2 x0 = *reinterpret_cast<const float2*>(h + (size_t)q0.x * HF + fo);
    float2 x1 = *reinterpret_cast<const float2*>(h + (size_t)q1.x * HF + fo);
    ax = fmaf(__int_as_float(q0.y), x0.x, ax); ay = fmaf(__int_as_float(q0.y), x0.y, ay);
    ax = fmaf(__int_as_float(q1.y), x1.x, ax); ay = fmaf(__int_as_float(q1.y), x1.y, ay);
    e += 2;
  }
  if (e < end) {
    int2 q0 = cv[e];
    float2 x0 = *reinterpret_cast<const float2*>(h + (size_t)q0.x * HF + fo);
    ax = fmaf(__int_as_float(q0.y), x0.x, ax); ay = fmaf(__int_as_float(q0.y), x0.y, ay);
  }
  *reinterpret_cast<float2*>(agg + (size_t)node * HF + fo) = make_float2(ax, ay);
}

// fp32 register-tiled GEMM — UNCHANGED from round 7 (instrumentation round:
// counters next round must reflect this exact structure).
__global__ __launch_bounds__(256) void k_gemm(const float* __restrict__ A, const float* __restrict__ W,
                                              const float* __restrict__ bias, float* __restrict__ out, int n) {
  __shared__ float As[32][132];  // [k][node], pad
  __shared__ float Ws[32][132];  // [k][col], pad
  const int tid = threadIdx.x;
  const int n0 = blockIdx.x * 128;
  const int ty = tid >> 4;  // 0..15
  const int tx = tid & 15;  // 0..15
  float acc[8][8];
#pragma unroll
  for (int i = 0; i < 8; i++)
#pragma unroll
    for (int j = 0; j < 8; j++) acc[i][j] = 0.f;

  for (int kc = 0; kc < HF; kc += 32) {
    {
      int kq = (tid & 7) * 4;
      int nl = tid >> 3;
#pragma unroll
      for (int p = 0; p < 4; ++p) {
        int nn = nl + p * 32;
        int ng = n0 + nn;
        float4 v = make_float4(0.f, 0.f, 0.f, 0.f);
        if (ng < n) v = *reinterpret_cast<const float4*>(A + (size_t)ng * HF + kc + kq);
        As[kq + 0][nn] = v.x;
        As[kq + 1][nn] = v.y;
        As[kq + 2][nn] = v.z;
        As[kq + 3][nn] = v.w;
      }
    }
    {
      int c4 = (tid & 31) * 4;
      int r = tid >> 5;
#pragma unroll
      for (int p = 0; p < 4; ++p) {
        int rr = r + p * 8;
        *reinterpret_cast<float4*>(&Ws[rr][c4]) =
            *reinterpret_cast<const float4*>(W + (size_t)(kc + rr) * HF + c4);
      }
    }
    __syncthreads();
#pragma unroll
    for (int k = 0; k < 32; ++k) {
      float4 a0 = *reinterpret_cast<const float4*>(&As[k][ty * 4]);
      float4 a1 = *reinterpret_cast<const float4*>(&As[k][ty * 4 + 64]);
      float4 w0 = *reinterpret_cast<const float4*>(&Ws[k][tx * 4]);
      float4 w1 = *reinterpret_cast<const float4*>(&Ws[k][tx * 4 + 64]);
      float av[8] = {a0.x, a0.y, a0.z, a0.w, a1.x, a1.y, a1.z, a1.w};
      float wv[8] = {w0.x, w0.y, w0.z, w0.w, w1.x, w1.y, w1.z, w1.w};
#pragma unroll
      for (int i = 0; i < 8; i++)
#pragma unroll
        for (int j = 0; j < 8; j++) acc[i][j] = fmaf(av[i], wv[j], acc[i][j]);
    }
    __syncthreads();
  }

  float4 bb0 = *reinterpret_cast<const float4*>(bias + tx * 4);
  float4 bb1 = *reinterpret_cast<const float4*>(bias + tx * 4 + 64);
  float bb[8] = {bb0.x, bb0.y, bb0.z, bb0.w, bb1.x, bb1.y, bb1.z, bb1.w};
#pragma unroll
  for (int g = 0; g < 2; ++g) {
#pragma unroll
    for (int i = 0; i < 4; ++i) {
      int node = n0 + ty * 4 + g * 64 + i;
      if (node < n) {
        int ai = g * 4 + i;
        float o[8];
#pragma unroll
        for (int j = 0; j < 8; j++) o[j] = leaky(acc[ai][j] + bb[j]);
        *reinterpret_cast<float4*>(out + (size_t)node * HF + tx * 4) = make_float4(o[0], o[1], o[2], o[3]);
        *reinterpret_cast<float4*>(out + (size_t)node * HF + tx * 4 + 64) = make_float4(o[4], o[5], o[6], o[7]);
      }
    }
  }
}

// ---------------- head ----------------

__global__ __launch_bounds__(256) void k_head(const float* __restrict__ h, const float* __restrict__ fcW,
                                              const float* __restrict__ fcb, float* __restrict__ out, int n) {
  int gw = (blockIdx.x * 256 + threadIdx.x) >> 6;
  int lane = threadIdx.x & 63;
  int node = gw * 8 + (lane >> 3);
  int part = lane & 7;
  float a0 = 0.f, a1 = 0.f, a2 = 0.f, a3 = 0.f;
  if (node < n) {
    const float* hp = h + (size_t)node * HF + part * 16;
#pragma unroll
    for (int i = 0; i < 16; i++) {
      float xv = hp[i];
      float4 wk = *reinterpret_cast<const float4*>(fcW + (part * 16 + i) * 4);
      a0 = fmaf(xv, wk.x, a0);
      a1 = fmaf(xv, wk.y, a1);
      a2 = fmaf(xv, wk.z, a2);
      a3 = fmaf(xv, wk.w, a3);
    }
  }
#pragma unroll
  for (int m = 1; m < 8; m <<= 1) {
    a0 += __shfl_xor(a0, m, 64);
    a1 += __shfl_xor(a1, m, 64);
    a2 += __shfl_xor(a2, m, 64);
    a3 += __shfl_xor(a3, m, 64);
  }
  if (part == 0 && node < n) {
    float4 o = make_float4(a0 + fcb[0], a1 + fcb[1], a2 + fcb[2], a3 + fcb[3]);
    *reinterpret_cast<float4*>(out + (size_t)node * 4) = o;
  }
}

// ---------------- launch ----------------

extern "C" void kernel_launch(void* const* d_in, const int* in_sizes, int n_in,
                              void* d_out, int out_size, void* d_ws, size_t ws_size,
                              hipStream_t stream) {
  const float* x = (const float*)d_in[0];
  const float* ew = (const float*)d_in[1];
  const int* src = (const int*)d_in[2];
  const int* dst = (const int*)d_in[3];
  const float* W1 = (const float*)d_in[4];
  const float* b1 = (const float*)d_in[5];
  const float* Wst = (const float*)d_in[6];
  const float* bst = (const float*)d_in[7];
  const float* fcW = (const float*)d_in[8];
  const float* fcb = (const float*)d_in[9];
  float* out = (float*)d_out;

  const int n = NN, e = NE;
  char* w = (char*)d_ws;
  size_t off = 0;
  auto alloc = [&](size_t bytes) {
    void* p = w + off;
    off += (bytes + 511) & ~(size_t)511;
    return p;
  };
  int* dout = (int*)alloc((size_t)n * 4);
  int* din = (int*)alloc((size_t)n * 4);
  float* iso = (float*)alloc((size_t)n * 4);
  float* isi = (float*)alloc((size_t)n * 4);
  int* rp = (int*)alloc((size_t)(n + 1) * 4);
  int* cursor = (int*)alloc((size_t)n * 4);
  int2* cv = (int2*)alloc((size_t)e * 8);
  float* h = (float*)alloc((size_t)n * HF * 4);
  float* agg = (float*)alloc((size_t)n * HF * 4);
  float* agg16 = agg;  // reuse

  hipMemsetAsync(dout, 0, (size_t)n * 4, stream);
  hipMemsetAsync(din, 0, (size_t)n * 4, stream);
  hipMemsetAsync(cursor, 0, (size_t)n * 4, stream);

  k_deg1<<<idiv(e, 1024), 256, 0, stream>>>(src, dout, e);
  k_deg1<<<idiv(e, 1024), 256, 0, stream>>>(dst, din, e);
  k_norms<<<idiv(n, 256), 256, 0, stream>>>(dout, din, iso, isi, n);
  k_scan<<<1, 1024, 0, stream>>>(din, rp, n);
  k_build<<<idiv(e, 256), 256, 0, stream>>>(src, dst, ew, iso, isi, rp, cursor, cv, e);

  k_spmm16<<<idiv(n * INF, 256), 256, 0, stream>>>(x, rp, cv, agg16, n);
  k_gemm16<<<idiv(n * HF, 256), 256, 0, stream>>>(agg16, W1, b1, h, n);

  // 3-way node-range split of spmm (instrumentation: pushes k_gemm into rocprof top-5)
  const int s1 = 33336, s2 = 66672;  // multiples of 4
  for (int l = 0; l < NLAYERS; ++l) {
    k_spmm<<<idiv(s1 - 0, 4), 256, 0, stream>>>(h, rp, cv, agg, 0, s1);
    k_spmm<<<idiv(s2 - s1, 4), 256, 0, stream>>>(h, rp, cv, agg, s1, s2);
    k_spmm<<<idiv(n - s2, 4), 256, 0, stream>>>(h, rp, cv, agg, s2, n);
    k_gemm<<<idiv(n, 128), 256, 0, stream>>>(agg, Wst + (size_t)l * HF * HF, bst + (size_t)l * HF, h, n);
  }
  k_head<<<idiv(n * 8, 256), 256, 0, stream>>>(h, fcW, fcb, out, n);
}

// Round 9
// 3716.672 us; speedup vs baseline: 1.0101x; 1.0101x over previous
//
#include <hip/hip_runtime.h>

#define NN 100000
#define NE 1600000
#define HF 128
#define INF 16
#define NLAYERS 19
#define NB_SCAN 98  // idiv(NN,1024)

static inline int idiv(int a, int b) { return (a + b - 1) / b; }

__device__ __forceinline__ float leaky(float v) { return (v >= 0.f) ? v : 0.01f * v; }

// ---------------- preprocessing ----------------

// histogram over edge range [e0,e1)
__global__ __launch_bounds__(256) void k_deg1(const int* __restrict__ idx, int* __restrict__ deg,
                                              int e0, int e1) {
  int i = e0 + (blockIdx.x * 256 + threadIdx.x) * 4;
  if (i + 4 <= e1) {
    int4 v = *reinterpret_cast<const int4*>(idx + i);
    atomicAdd(&deg[v.x], 1);
    atomicAdd(&deg[v.y], 1);
    atomicAdd(&deg[v.z], 1);
    atomicAdd(&deg[v.w], 1);
  } else {
    for (; i < e1; ++i) atomicAdd(&deg[idx[i]], 1);
  }
}

__global__ __launch_bounds__(256) void k_norms(const int* __restrict__ dout, const int* __restrict__ din,
                                               float* __restrict__ iso, float* __restrict__ isi, int n) {
  int i = blockIdx.x * 256 + threadIdx.x;
  if (i < n) {
    iso[i] = rsqrtf((float)(dout[i] > 1 ? dout[i] : 1));
    isi[i] = rsqrtf((float)(din[i] > 1 ? din[i] : 1));
  }
}

// ---- multi-block scan (3 kernels): per-block sums -> scan partials -> final ----

__global__ __launch_bounds__(1024) void k_scan_part(const int* __restrict__ cnt, int* __restrict__ bsum, int n) {
  __shared__ int wsum[16];
  const int tid = threadIdx.x;
  const int lane = tid & 63;
  const int wid = tid >> 6;
  int i = blockIdx.x * 1024 + tid;
  int v = (i < n) ? cnt[i] : 0;
  int s = v;
#pragma unroll
  for (int m = 1; m < 64; m <<= 1) s += __shfl_xor(s, m, 64);
  if (lane == 0) wsum[wid] = s;
  __syncthreads();
  if (tid == 0) {
    int t = 0;
#pragma unroll
    for (int j = 0; j < 16; j++) t += wsum[j];
    bsum[blockIdx.x] = t;
  }
}

// single tiny block: exclusive-scan the NB_SCAN partials; also writes rp[n] total
__global__ __launch_bounds__(128) void k_scan_small(const int* __restrict__ bsum, int* __restrict__ boff,
                                                    int* __restrict__ rp, int n, int nb) {
  __shared__ int ws[2];
  const int tid = threadIdx.x;
  const int lane = tid & 63;
  const int wid = tid >> 6;
  int v = (tid < nb) ? bsum[tid] : 0;
  int x = v;
#pragma unroll
  for (int off = 1; off < 64; off <<= 1) {
    int t = __shfl_up(x, off, 64);
    if (lane >= off) x += t;
  }
  if (lane == 63) ws[wid] = x;
  __syncthreads();
  int add = (wid > 0) ? ws[0] : 0;
  if (tid < nb) boff[tid] = add + x - v;
  if (tid == 127) rp[n] = ws[0] + x;
}

__global__ __launch_bounds__(1024) void k_scan_final(const int* __restrict__ cnt, const int* __restrict__ boff,
                                                     int* __restrict__ rp, int n) {
  __shared__ int wsum[16];
  const int tid = threadIdx.x;
  const int lane = tid & 63;
  const int wid = tid >> 6;
  int i = blockIdx.x * 1024 + tid;
  int v = (i < n) ? cnt[i] : 0;
  int x = v;
#pragma unroll
  for (int off = 1; off < 64; off <<= 1) {
    int t = __shfl_up(x, off, 64);
    if (lane >= off) x += t;
  }
  if (lane == 63) wsum[wid] = x;
  __syncthreads();
  if (wid == 0) {
    int s = (lane < 16) ? wsum[lane] : 0;
#pragma unroll
    for (int off = 1; off < 16; off <<= 1) {
      int t = __shfl_up(s, off, 64);
      if (lane >= off) s += t;
    }
    if (lane < 16) wsum[lane] = s;
  }
  __syncthreads();
  int woff = (wid > 0) ? wsum[wid - 1] : 0;
  if (i < n) rp[i] = boff[blockIdx.x] + woff + x - v;
}

// build packed CSR over edge range [e0,e1): cv[pos] = {col, bits(val)}
__global__ __launch_bounds__(256) void k_build(const int* __restrict__ src, const int* __restrict__ dst,
                                               const float* __restrict__ ew, const float* __restrict__ iso,
                                               const float* __restrict__ isi, const int* __restrict__ rp,
                                               int* __restrict__ cursor, int2* __restrict__ cv,
                                               int e0, int e1) {
  int i = e0 + blockIdx.x * 256 + threadIdx.x;
  if (i < e1) {
    int s = src[i], d = dst[i];
    int pos = rp[d] + atomicAdd(&cursor[d], 1);
    float v = ew[i] * iso[s] * isi[d];
    cv[pos] = make_int2(s, __float_as_int(v));
  }
}

// ---------------- layer 1 (16 feats) ----------------

__global__ __launch_bounds__(256) void k_spmm16(const float* __restrict__ x, const int* __restrict__ rp,
                                                const int2* __restrict__ cv, float* __restrict__ agg16, int n) {
  int t = blockIdx.x * 256 + threadIdx.x;
  int node = t >> 4, f = t & 15;
  if (node >= n) return;
  int e = rp[node], end = rp[node + 1];
  float a = 0.f;
  for (; e + 4 <= end; e += 4) {
    int2 q0 = cv[e], q1 = cv[e + 1], q2 = cv[e + 2], q3 = cv[e + 3];
    float x0 = x[(size_t)q0.x * INF + f];
    float x1 = x[(size_t)q1.x * INF + f];
    float x2 = x[(size_t)q2.x * INF + f];
    float x3 = x[(size_t)q3.x * INF + f];
    a = fmaf(__int_as_float(q0.y), x0, a);
    a = fmaf(__int_as_float(q1.y), x1, a);
    a = fmaf(__int_as_float(q2.y), x2, a);
    a = fmaf(__int_as_float(q3.y), x3, a);
  }
  for (; e < end; ++e) {
    int2 q = cv[e];
    a = fmaf(__int_as_float(q.y), x[(size_t)q.x * INF + f], a);
  }
  agg16[(size_t)node * INF + f] = a;
}

__global__ __launch_bounds__(256) void k_gemm16(const float* __restrict__ agg16, const float* __restrict__ W1,
                                                const float* __restrict__ b1, float* __restrict__ h, int n) {
  __shared__ float W1s[INF * HF];
  int tid = threadIdx.x;
  {
    float4* d4 = reinterpret_cast<float4*>(W1s);
    const float4* s4 = reinterpret_cast<const float4*>(W1);
    d4[tid] = s4[tid];
    d4[tid + 256] = s4[tid + 256];
  }
  __syncthreads();
  int t = blockIdx.x * 256 + tid;
  int node = t >> 7, c = t & 127;
  if (node >= n) return;
  const float* ar = agg16 + (size_t)node * INF;
  float4 a0 = *reinterpret_cast<const float4*>(ar);
  float4 a1 = *reinterpret_cast<const float4*>(ar + 4);
  float4 a2 = *reinterpret_cast<const float4*>(ar + 8);
  float4 a3 = *reinterpret_cast<const float4*>(ar + 12);
  float av[16] = {a0.x, a0.y, a0.z, a0.w, a1.x, a1.y, a1.z, a1.w,
                  a2.x, a2.y, a2.z, a2.w, a3.x, a3.y, a3.z, a3.w};
  float a = b1[c];
#pragma unroll
  for (int f = 0; f < INF; ++f) a = fmaf(av[f], W1s[f * HF + c], a);
  h[(size_t)t] = leaky(a);
}

// ---------------- hidden layers ----------------

// wave-per-node, float2 per lane, 8-deep gather pipeline (at fabric BW ceiling).
// Node-range split [n0, n1): telemetry aid, spmm itself is closed at its traffic floor.
__global__ __launch_bounds__(256) void k_spmm(const float* __restrict__ h, const int* __restrict__ rp,
                                              const int2* __restrict__ cv, float* __restrict__ agg,
                                              int n0, int n1) {
  const int lane = threadIdx.x & 63;
  const int node = __builtin_amdgcn_readfirstlane(n0 + blockIdx.x * 4 + (threadIdx.x >> 6));
  if (node >= n1) return;
  const int beg = rp[node], end = rp[node + 1];
  const size_t fo = (size_t)(lane << 1);
  float ax = 0.f, ay = 0.f;
  int e = beg;
  for (; e + 8 <= end; e += 8) {
    int2 q0 = cv[e + 0], q1 = cv[e + 1], q2 = cv[e + 2], q3 = cv[e + 3];
    int2 q4 = cv[e + 4], q5 = cv[e + 5], q6 = cv[e + 6], q7 = cv[e + 7];
    float2 x0 = *reinterpret_cast<const float2*>(h + (size_t)q0.x * HF + fo);
    float2 x1 = *reinterpret_cast<const float2*>(h + (size_t)q1.x * HF + fo);
    float2 x2 = *reinterpret_cast<const float2*>(h + (size_t)q2.x * HF + fo);
    float2 x3 = *reinterpret_cast<const float2*>(h + (size_t)q3.x * HF + fo);
    float2 x4 = *reinterpret_cast<const float2*>(h + (size_t)q4.x * HF + fo);
    float2 x5 = *reinterpret_cast<const float2*>(h + (size_t)q5.x * HF + fo);
    float2 x6 = *reinterpret_cast<const float2*>(h + (size_t)q6.x * HF + fo);
    float2 x7 = *reinterpret_cast<const float2*>(h + (size_t)q7.x * HF + fo);
    ax = fmaf(__int_as_float(q0.y), x0.x, ax); ay = fmaf(__int_as_float(q0.y), x0.y, ay);
    ax = fmaf(__int_as_float(q1.y), x1.x, ax); ay = fmaf(__int_as_float(q1.y), x1.y, ay);
    ax = fmaf(__int_as_float(q2.y), x2.x, ax); ay = fmaf(__int_as_float(q2.y), x2.y, ay);
    ax = fmaf(__int_as_float(q3.y), x3.x, ax); ay = fmaf(__int_as_float(q3.y), x3.y, ay);
    ax = fmaf(__int_as_float(q4.y), x4.x, ax); ay = fmaf(__int_as_float(q4.y), x4.y, ay);
    ax = fmaf(__int_as_float(q5.y), x5.x, ax); ay = fmaf(__int_as_float(q5.y), x5.y, ay);
    ax = fmaf(__int_as_float(q6.y), x6.x, ax); ay = fmaf(__int_as_float(q6.y), x6.y, ay);
    ax = fmaf(__int_as_float(q7.y), x7.x, ax); ay = fmaf(__int_as_float(q7.y), x7.y, ay);
  }
  if (e + 4 <= end) {
    int2 q0 = cv[e + 0], q1 = cv[e + 1], q2 = cv[e + 2], q3 = cv[e + 3];
    float2 x0 = *reinterpret_cast<const float2*>(h + (size_t)q0.x * HF + fo);
    float2 x1 = *reinterpret_cast<const float2*>(h + (size_t)q1.x * HF + fo);
    float2 x2 = *reinterpret_cast<const float2*>(h + (size_t)q2.x * HF + fo);
    float2 x3 = *reinterpret_cast<const float2*>(h + (size_t)q3.x * HF + fo);
    ax = fmaf(__int_as_float(q0.y), x0.x, ax); ay = fmaf(__int_as_float(q0.y), x0.y, ay);
    ax = fmaf(__int_as_float(q1.y), x1.x, ax); ay = fmaf(__int_as_float(q1.y), x1.y, ay);
    ax = fmaf(__int_as_float(q2.y), x2.x, ax); ay = fmaf(__int_as_float(q2.y), x2.y, ay);
    ax = fmaf(__int_as_float(q3.y), x3.x, ax); ay = fmaf(__int_as_float(q3.y), x3.y, ay);
    e += 4;
  }
  if (e + 2 <= end) {
    int2 q0 = cv[e + 0], q1 = cv[e + 1];
    float2 x0 = *reinterpret_cast<const float2*>(h + (size_t)q0.x * HF + fo);
    float2 x1 = *reinterpret_cast<const float2*>(h + (size_t)q1.x * HF + fo);
    ax = fmaf(__int_as_float(q0.y), x0.x, ax); ay = fmaf(__int_as_float(q0.y), x0.y, ay);
    ax = fmaf(__int_as_float(q1.y), x1.x, ax); ay = fmaf(__int_as_float(q1.y), x1.y, ay);
    e += 2;
  }
  if (e < end) {
    int2 q0 = cv[e];
    float2 x0 = *reinterpret_cast<const float2*>(h + (size_t)q0.x * HF + fo);
    ax = fmaf(__int_as_float(q0.y), x0.x, ax); ay = fmaf(__int_as_float(q0.y), x0.y, ay);
  }
  *reinterpret_cast<float2*>(agg + (size_t)node * HF + fo) = make_float2(ax, ay);
}

// fp32 register-tiled GEMM — UNCHANGED (counters for this exact structure arrive next round)
__global__ __launch_bounds__(256) void k_gemm(const float* __restrict__ A, const float* __restrict__ W,
                                              const float* __restrict__ bias, float* __restrict__ out, int n) {
  __shared__ float As[32][132];  // [k][node], pad
  __shared__ float Ws[32][132];  // [k][col], pad
  const int tid = threadIdx.x;
  const int n0 = blockIdx.x * 128;
  const int ty = tid >> 4;  // 0..15
  const int tx = tid & 15;  // 0..15
  float acc[8][8];
#pragma unroll
  for (int i = 0; i < 8; i++)
#pragma unroll
    for (int j = 0; j < 8; j++) acc[i][j] = 0.f;

  for (int kc = 0; kc < HF; kc += 32) {
    {
      int kq = (tid & 7) * 4;
      int nl = tid >> 3;
#pragma unroll
      for (int p = 0; p < 4; ++p) {
        int nn = nl + p * 32;
        int ng = n0 + nn;
        float4 v = make_float4(0.f, 0.f, 0.f, 0.f);
        if (ng < n) v = *reinterpret_cast<const float4*>(A + (size_t)ng * HF + kc + kq);
        As[kq + 0][nn] = v.x;
        As[kq + 1][nn] = v.y;
        As[kq + 2][nn] = v.z;
        As[kq + 3][nn] = v.w;
      }
    }
    {
      int c4 = (tid & 31) * 4;
      int r = tid >> 5;
#pragma unroll
      for (int p = 0; p < 4; ++p) {
        int rr = r + p * 8;
        *reinterpret_cast<float4*>(&Ws[rr][c4]) =
            *reinterpret_cast<const float4*>(W + (size_t)(kc + rr) * HF + c4);
      }
    }
    __syncthreads();
#pragma unroll
    for (int k = 0; k < 32; ++k) {
      float4 a0 = *reinterpret_cast<const float4*>(&As[k][ty * 4]);
      float4 a1 = *reinterpret_cast<const float4*>(&As[k][ty * 4 + 64]);
      float4 w0 = *reinterpret_cast<const float4*>(&Ws[k][tx * 4]);
      float4 w1 = *reinterpret_cast<const float4*>(&Ws[k][tx * 4 + 64]);
      float av[8] = {a0.x, a0.y, a0.z, a0.w, a1.x, a1.y, a1.z, a1.w};
      float wv[8] = {w0.x, w0.y, w0.z, w0.w, w1.x, w1.y, w1.z, w1.w};
#pragma unroll
      for (int i = 0; i < 8; i++)
#pragma unroll
        for (int j = 0; j < 8; j++) acc[i][j] = fmaf(av[i], wv[j], acc[i][j]);
    }
    __syncthreads();
  }

  float4 bb0 = *reinterpret_cast<const float4*>(bias + tx * 4);
  float4 bb1 = *reinterpret_cast<const float4*>(bias + tx * 4 + 64);
  float bb[8] = {bb0.x, bb0.y, bb0.z, bb0.w, bb1.x, bb1.y, bb1.z, bb1.w};
#pragma unroll
  for (int g = 0; g < 2; ++g) {
#pragma unroll
    for (int i = 0; i < 4; ++i) {
      int node = n0 + ty * 4 + g * 64 + i;
      if (node < n) {
        int ai = g * 4 + i;
        float o[8];
#pragma unroll
        for (int j = 0; j < 8; j++) o[j] = leaky(acc[ai][j] + bb[j]);
        *reinterpret_cast<float4*>(out + (size_t)node * HF + tx * 4) = make_float4(o[0], o[1], o[2], o[3]);
        *reinterpret_cast<float4*>(out + (size_t)node * HF + tx * 4 + 64) = make_float4(o[4], o[5], o[6], o[7]);
      }
    }
  }
}

// ---------------- head ----------------

__global__ __launch_bounds__(256) void k_head(const float* __restrict__ h, const float* __restrict__ fcW,
                                              const float* __restrict__ fcb, float* __restrict__ out, int n) {
  int gw = (blockIdx.x * 256 + threadIdx.x) >> 6;
  int lane = threadIdx.x & 63;
  int node = gw * 8 + (lane >> 3);
  int part = lane & 7;
  float a0 = 0.f, a1 = 0.f, a2 = 0.f, a3 = 0.f;
  if (node < n) {
    const float* hp = h + (size_t)node * HF + part * 16;
#pragma unroll
    for (int i = 0; i < 16; i++) {
      float xv = hp[i];
      float4 wk = *reinterpret_cast<const float4*>(fcW + (part * 16 + i) * 4);
      a0 = fmaf(xv, wk.x, a0);
      a1 = fmaf(xv, wk.y, a1);
      a2 = fmaf(xv, wk.z, a2);
      a3 = fmaf(xv, wk.w, a3);
    }
  }
#pragma unroll
  for (int m = 1; m < 8; m <<= 1) {
    a0 += __shfl_xor(a0, m, 64);
    a1 += __shfl_xor(a1, m, 64);
    a2 += __shfl_xor(a2, m, 64);
    a3 += __shfl_xor(a3, m, 64);
  }
  if (part == 0 && node < n) {
    float4 o = make_float4(a0 + fcb[0], a1 + fcb[1], a2 + fcb[2], a3 + fcb[3]);
    *reinterpret_cast<float4*>(out + (size_t)node * 4) = o;
  }
}

// ---------------- launch ----------------

extern "C" void kernel_launch(void* const* d_in, const int* in_sizes, int n_in,
                              void* d_out, int out_size, void* d_ws, size_t ws_size,
                              hipStream_t stream) {
  const float* x = (const float*)d_in[0];
  const float* ew = (const float*)d_in[1];
  const int* src = (const int*)d_in[2];
  const int* dst = (const int*)d_in[3];
  const float* W1 = (const float*)d_in[4];
  const float* b1 = (const float*)d_in[5];
  const float* Wst = (const float*)d_in[6];
  const float* bst = (const float*)d_in[7];
  const float* fcW = (const float*)d_in[8];
  const float* fcb = (const float*)d_in[9];
  float* out = (float*)d_out;

  const int n = NN, e = NE;
  char* w = (char*)d_ws;
  size_t off = 0;
  auto alloc = [&](size_t bytes) {
    void* p = w + off;
    off += (bytes + 511) & ~(size_t)511;
    return p;
  };
  int* dout = (int*)alloc((size_t)n * 4);
  int* din = (int*)alloc((size_t)n * 4);
  float* iso = (float*)alloc((size_t)n * 4);
  float* isi = (float*)alloc((size_t)n * 4);
  int* rp = (int*)alloc((size_t)(n + 1) * 4);
  int* cursor = (int*)alloc((size_t)n * 4);
  int* bsum = (int*)alloc((size_t)NB_SCAN * 4);
  int* boff = (int*)alloc((size_t)NB_SCAN * 4);
  int2* cv = (int2*)alloc((size_t)e * 8);
  float* h = (float*)alloc((size_t)n * HF * 4);
  float* agg = (float*)alloc((size_t)n * HF * 4);
  float* agg16 = agg;  // reuse

  hipMemsetAsync(dout, 0, (size_t)n * 4, stream);
  hipMemsetAsync(din, 0, (size_t)n * 4, stream);
  hipMemsetAsync(cursor, 0, (size_t)n * 4, stream);

  const int eh = 800000;  // e/2, multiple of 4
  k_deg1<<<idiv(eh, 1024), 256, 0, stream>>>(src, dout, 0, eh);
  k_deg1<<<idiv(e - eh, 1024), 256, 0, stream>>>(src, dout, eh, e);
  k_deg1<<<idiv(eh, 1024), 256, 0, stream>>>(dst, din, 0, eh);
  k_deg1<<<idiv(e - eh, 1024), 256, 0, stream>>>(dst, din, eh, e);
  k_norms<<<idiv(n, 256), 256, 0, stream>>>(dout, din, iso, isi, n);

  k_scan_part<<<NB_SCAN, 1024, 0, stream>>>(din, bsum, n);
  k_scan_small<<<1, 128, 0, stream>>>(bsum, boff, rp, n, NB_SCAN);
  k_scan_final<<<NB_SCAN, 1024, 0, stream>>>(din, boff, rp, n);

  k_build<<<idiv(eh, 256), 256, 0, stream>>>(src, dst, ew, iso, isi, rp, cursor, cv, 0, eh);
  k_build<<<idiv(e - eh, 256), 256, 0, stream>>>(src, dst, ew, iso, isi, rp, cursor, cv, eh, e);

  k_spmm16<<<idiv(n * INF, 256), 256, 0, stream>>>(x, rp, cv, agg16, n);
  k_gemm16<<<idiv(n * HF, 256), 256, 0, stream>>>(agg16, W1, b1, h, n);

  // 3-way node-range split of spmm (telemetry: keeps k_gemm in rocprof top-5)
  const int s1 = 33336, s2 = 66672;  // multiples of 4
  for (int l = 0; l < NLAYERS; ++l) {
    k_spmm<<<idiv(s1 - 0, 4), 256, 0, stream>>>(h, rp, cv, agg, 0, s1);
    k_spmm<<<idiv(s2 - s1, 4), 256, 0, stream>>>(h, rp, cv, agg, s1, s2);
    k_spmm<<<idiv(n - s2, 4), 256, 0, stream>>>(h, rp, cv, agg, s2, n);
    k_gemm<<<idiv(n, 128), 256, 0, stream>>>(agg, Wst + (size_t)l * HF * HF, bst + (size_t)l * HF, h, n);
  }
  k_head<<<idiv(n * 8, 256), 256, 0, stream>>>(h, fcW, fcb, out, n);
}

// Round 10
// 3504.801 us; speedup vs baseline: 1.0712x; 1.0605x over previous
//
#include <hip/hip_runtime.h>

#define NN 100000
#define NE 1600000
#define HF 128
#define INF 16
#define NLAYERS 19
#define NB_SCAN 98  // idiv(NN,1024)

static inline int idiv(int a, int b) { return (a + b - 1) / b; }

__device__ __forceinline__ float leaky(float v) { return (v >= 0.f) ? v : 0.01f * v; }

// ---------------- preprocessing ----------------

// histogram over edge range [e0,e1)
__global__ __launch_bounds__(256) void k_deg1(const int* __restrict__ idx, int* __restrict__ deg,
                                              int e0, int e1) {
  int i = e0 + (blockIdx.x * 256 + threadIdx.x) * 4;
  if (i + 4 <= e1) {
    int4 v = *reinterpret_cast<const int4*>(idx + i);
    atomicAdd(&deg[v.x], 1);
    atomicAdd(&deg[v.y], 1);
    atomicAdd(&deg[v.z], 1);
    atomicAdd(&deg[v.w], 1);
  } else {
    for (; i < e1; ++i) atomicAdd(&deg[idx[i]], 1);
  }
}

__global__ __launch_bounds__(256) void k_norms(const int* __restrict__ dout, const int* __restrict__ din,
                                               float* __restrict__ iso, float* __restrict__ isi, int n) {
  int i = blockIdx.x * 256 + threadIdx.x;
  if (i < n) {
    iso[i] = rsqrtf((float)(dout[i] > 1 ? dout[i] : 1));
    isi[i] = rsqrtf((float)(din[i] > 1 ? din[i] : 1));
  }
}

// ---- multi-block scan (3 kernels) ----

__global__ __launch_bounds__(1024) void k_scan_part(const int* __restrict__ cnt, int* __restrict__ bsum, int n) {
  __shared__ int wsum[16];
  const int tid = threadIdx.x;
  const int lane = tid & 63;
  const int wid = tid >> 6;
  int i = blockIdx.x * 1024 + tid;
  int v = (i < n) ? cnt[i] : 0;
  int s = v;
#pragma unroll
  for (int m = 1; m < 64; m <<= 1) s += __shfl_xor(s, m, 64);
  if (lane == 0) wsum[wid] = s;
  __syncthreads();
  if (tid == 0) {
    int t = 0;
#pragma unroll
    for (int j = 0; j < 16; j++) t += wsum[j];
    bsum[blockIdx.x] = t;
  }
}

__global__ __launch_bounds__(128) void k_scan_small(const int* __restrict__ bsum, int* __restrict__ boff,
                                                    int* __restrict__ rp, int n, int nb) {
  __shared__ int ws[2];
  const int tid = threadIdx.x;
  const int lane = tid & 63;
  const int wid = tid >> 6;
  int v = (tid < nb) ? bsum[tid] : 0;
  int x = v;
#pragma unroll
  for (int off = 1; off < 64; off <<= 1) {
    int t = __shfl_up(x, off, 64);
    if (lane >= off) x += t;
  }
  if (lane == 63) ws[wid] = x;
  __syncthreads();
  int add = (wid > 0) ? ws[0] : 0;
  if (tid < nb) boff[tid] = add + x - v;
  if (tid == 127) rp[n] = ws[0] + x;
}

__global__ __launch_bounds__(1024) void k_scan_final(const int* __restrict__ cnt, const int* __restrict__ boff,
                                                     int* __restrict__ rp, int n) {
  __shared__ int wsum[16];
  const int tid = threadIdx.x;
  const int lane = tid & 63;
  const int wid = tid >> 6;
  int i = blockIdx.x * 1024 + tid;
  int v = (i < n) ? cnt[i] : 0;
  int x = v;
#pragma unroll
  for (int off = 1; off < 64; off <<= 1) {
    int t = __shfl_up(x, off, 64);
    if (lane >= off) x += t;
  }
  if (lane == 63) wsum[wid] = x;
  __syncthreads();
  if (wid == 0) {
    int s = (lane < 16) ? wsum[lane] : 0;
#pragma unroll
    for (int off = 1; off < 16; off <<= 1) {
      int t = __shfl_up(s, off, 64);
      if (lane >= off) s += t;
    }
    if (lane < 16) wsum[lane] = s;
  }
  __syncthreads();
  int woff = (wid > 0) ? wsum[wid - 1] : 0;
  if (i < n) rp[i] = boff[blockIdx.x] + woff + x - v;
}

// build packed CSR over edge range [e0,e1): cv[pos] = {col, bits(val)}
__global__ __launch_bounds__(256) void k_build(const int* __restrict__ src, const int* __restrict__ dst,
                                               const float* __restrict__ ew, const float* __restrict__ iso,
                                               const float* __restrict__ isi, const int* __restrict__ rp,
                                               int* __restrict__ cursor, int2* __restrict__ cv,
                                               int e0, int e1) {
  int i = e0 + blockIdx.x * 256 + threadIdx.x;
  if (i < e1) {
    int s = src[i], d = dst[i];
    int pos = rp[d] + atomicAdd(&cursor[d], 1);
    float v = ew[i] * iso[s] * isi[d];
    cv[pos] = make_int2(s, __float_as_int(v));
  }
}

// ---------------- layer 1 (16 feats) ----------------

__global__ __launch_bounds__(256) void k_spmm16(const float* __restrict__ x, const int* __restrict__ rp,
                                                const int2* __restrict__ cv, float* __restrict__ agg16, int n) {
  int t = blockIdx.x * 256 + threadIdx.x;
  int node = t >> 4, f = t & 15;
  if (node >= n) return;
  int e = rp[node], end = rp[node + 1];
  float a = 0.f;
  for (; e + 4 <= end; e += 4) {
    int2 q0 = cv[e], q1 = cv[e + 1], q2 = cv[e + 2], q3 = cv[e + 3];
    float x0 = x[(size_t)q0.x * INF + f];
    float x1 = x[(size_t)q1.x * INF + f];
    float x2 = x[(size_t)q2.x * INF + f];
    float x3 = x[(size_t)q3.x * INF + f];
    a = fmaf(__int_as_float(q0.y), x0, a);
    a = fmaf(__int_as_float(q1.y), x1, a);
    a = fmaf(__int_as_float(q2.y), x2, a);
    a = fmaf(__int_as_float(q3.y), x3, a);
  }
  for (; e < end; ++e) {
    int2 q = cv[e];
    a = fmaf(__int_as_float(q.y), x[(size_t)q.x * INF + f], a);
  }
  agg16[(size_t)node * INF + f] = a;
}

__global__ __launch_bounds__(256) void k_gemm16(const float* __restrict__ agg16, const float* __restrict__ W1,
                                                const float* __restrict__ b1, float* __restrict__ h, int n) {
  __shared__ float W1s[INF * HF];
  int tid = threadIdx.x;
  {
    float4* d4 = reinterpret_cast<float4*>(W1s);
    const float4* s4 = reinterpret_cast<const float4*>(W1);
    d4[tid] = s4[tid];
    d4[tid + 256] = s4[tid + 256];
  }
  __syncthreads();
  int t = blockIdx.x * 256 + tid;
  int node = t >> 7, c = t & 127;
  if (node >= n) return;
  const float* ar = agg16 + (size_t)node * INF;
  float4 a0 = *reinterpret_cast<const float4*>(ar);
  float4 a1 = *reinterpret_cast<const float4*>(ar + 4);
  float4 a2 = *reinterpret_cast<const float4*>(ar + 8);
  float4 a3 = *reinterpret_cast<const float4*>(ar + 12);
  float av[16] = {a0.x, a0.y, a0.z, a0.w, a1.x, a1.y, a1.z, a1.w,
                  a2.x, a2.y, a2.z, a2.w, a3.x, a3.y, a3.z, a3.w};
  float a = b1[c];
#pragma unroll
  for (int f = 0; f < INF; ++f) a = fmaf(av[f], W1s[f * HF + c], a);
  h[(size_t)t] = leaky(a);
}

// ---------------- hidden layers ----------------

// wave-per-node, float2 per lane, 8-deep gather pipeline (at fabric BW ceiling).
__global__ __launch_bounds__(256) void k_spmm(const float* __restrict__ h, const int* __restrict__ rp,
                                              const int2* __restrict__ cv, float* __restrict__ agg,
                                              int n0, int n1) {
  const int lane = threadIdx.x & 63;
  const int node = __builtin_amdgcn_readfirstlane(n0 + blockIdx.x * 4 + (threadIdx.x >> 6));
  if (node >= n1) return;
  const int beg = rp[node], end = rp[node + 1];
  const size_t fo = (size_t)(lane << 1);
  float ax = 0.f, ay = 0.f;
  int e = beg;
  for (; e + 8 <= end; e += 8) {
    int2 q0 = cv[e + 0], q1 = cv[e + 1], q2 = cv[e + 2], q3 = cv[e + 3];
    int2 q4 = cv[e + 4], q5 = cv[e + 5], q6 = cv[e + 6], q7 = cv[e + 7];
    float2 x0 = *reinterpret_cast<const float2*>(h + (size_t)q0.x * HF + fo);
    float2 x1 = *reinterpret_cast<const float2*>(h + (size_t)q1.x * HF + fo);
    float2 x2 = *reinterpret_cast<const float2*>(h + (size_t)q2.x * HF + fo);
    float2 x3 = *reinterpret_cast<const float2*>(h + (size_t)q3.x * HF + fo);
    float2 x4 = *reinterpret_cast<const float2*>(h + (size_t)q4.x * HF + fo);
    float2 x5 = *reinterpret_cast<const float2*>(h + (size_t)q5.x * HF + fo);
    float2 x6 = *reinterpret_cast<const float2*>(h + (size_t)q6.x * HF + fo);
    float2 x7 = *reinterpret_cast<const float2*>(h + (size_t)q7.x * HF + fo);
    ax = fmaf(__int_as_float(q0.y), x0.x, ax); ay = fmaf(__int_as_float(q0.y), x0.y, ay);
    ax = fmaf(__int_as_float(q1.y), x1.x, ax); ay = fmaf(__int_as_float(q1.y), x1.y, ay);
    ax = fmaf(__int_as_float(q2.y), x2.x, ax); ay = fmaf(__int_as_float(q2.y), x2.y, ay);
    ax = fmaf(__int_as_float(q3.y), x3.x, ax); ay = fmaf(__int_as_float(q3.y), x3.y, ay);
    ax = fmaf(__int_as_float(q4.y), x4.x, ax); ay = fmaf(__int_as_float(q4.y), x4.y, ay);
    ax = fmaf(__int_as_float(q5.y), x5.x, ax); ay = fmaf(__int_as_float(q5.y), x5.y, ay);
    ax = fmaf(__int_as_float(q6.y), x6.x, ax); ay = fmaf(__int_as_float(q6.y), x6.y, ay);
    ax = fmaf(__int_as_float(q7.y), x7.x, ax); ay = fmaf(__int_as_float(q7.y), x7.y, ay);
  }
  if (e + 4 <= end) {
    int2 q0 = cv[e + 0], q1 = cv[e + 1], q2 = cv[e + 2], q3 = cv[e + 3];
    float2 x0 = *reinterpret_cast<const float2*>(h + (size_t)q0.x * HF + fo);
    float2 x1 = *reinterpret_cast<const float2*>(h + (size_t)q1.x * HF + fo);
    float2 x2 = *reinterpret_cast<const float2*>(h + (size_t)q2.x * HF + fo);
    float2 x3 = *reinterpret_cast<const float2*>(h + (size_t)q3.x * HF + fo);
    ax = fmaf(__int_as_float(q0.y), x0.x, ax); ay = fmaf(__int_as_float(q0.y), x0.y, ay);
    ax = fmaf(__int_as_float(q1.y), x1.x, ax); ay = fmaf(__int_as_float(q1.y), x1.y, ay);
    ax = fmaf(__int_as_float(q2.y), x2.x, ax); ay = fmaf(__int_as_float(q2.y), x2.y, ay);
    ax = fmaf(__int_as_float(q3.y), x3.x, ax); ay = fmaf(__int_as_float(q3.y), x3.y, ay);
    e += 4;
  }
  if (e + 2 <= end) {
    int2 q0 = cv[e + 0], q1 = cv[e + 1];
    float2 x0 = *reinterpret_cast<const float2*>(h + (size_t)q0.x * HF + fo);
    float2 x1 = *reinterpret_cast<const float2*>(h + (size_t)q1.x * HF + fo);
    ax = fmaf(__int_as_float(q0.y), x0.x, ax); ay = fmaf(__int_as_float(q0.y), x0.y, ay);
    ax = fmaf(__int_as_float(q1.y), x1.x, ax); ay = fmaf(__int_as_float(q1.y), x1.y, ay);
    e += 2;
  }
  if (e < end) {
    int2 q0 = cv[e];
    float2 x0 = *reinterpret_cast<const float2*>(h + (size_t)q0.x * HF + fo);
    ax = fmaf(__int_as_float(q0.y), x0.x, ax); ay = fmaf(__int_as_float(q0.y), x0.y, ay);
  }
  *reinterpret_cast<float2*>(agg + (size_t)node * HF + fo) = make_float2(ax, ay);
}

// fp32 register-tiled GEMM: 64 nodes x 128 cols per block, 4x8 per thread, K-chunk 32.
// Smaller tile -> 1563 blocks (~6/CU), LDS 25.4KB (6 blocks/CU), acc 4x8 -> VGPR ~70.
// Occupancy-driven fix for the 38%-VALUBusy barrier stall (round-9 counters).
__global__ __launch_bounds__(256, 6) void k_gemm(const float* __restrict__ A, const float* __restrict__ W,
                                                 const float* __restrict__ bias, float* __restrict__ out, int n) {
  __shared__ float As[32][66];   // [k][node], stride 66 (8B-aligned rows, 2-way store alias)
  __shared__ float Ws[32][132];  // [k][col], pad (proven)
  const int tid = threadIdx.x;
  const int n0 = blockIdx.x * 64;
  const int ty = tid >> 4;  // 0..15 -> node quad ty*4
  const int tx = tid & 15;  // 0..15 -> col quads {tx*4, tx*4+64}
  float acc[4][8];
#pragma unroll
  for (int i = 0; i < 4; i++)
#pragma unroll
    for (int j = 0; j < 8; j++) acc[i][j] = 0.f;

  for (int kc = 0; kc < HF; kc += 32) {
    // A stage: 64 nodes x 32 k = 512 float4, 2 per thread
    {
      int node = tid >> 2;
      int ng = n0 + node;
#pragma unroll
      for (int i = 0; i < 2; ++i) {
        int kq = ((tid & 3) * 2 + i) * 4;
        float4 v = make_float4(0.f, 0.f, 0.f, 0.f);
        if (ng < n) v = *reinterpret_cast<const float4*>(A + (size_t)ng * HF + kc + kq);
        As[kq + 0][node] = v.x;
        As[kq + 1][node] = v.y;
        As[kq + 2][node] = v.z;
        As[kq + 3][node] = v.w;
      }
    }
    // W stage: 32 x 128 = 1024 float4, 4 per thread (proven map)
    {
      int c4 = (tid & 31) * 4;
      int r = tid >> 5;
#pragma unroll
      for (int p = 0; p < 4; ++p) {
        int rr = r + p * 8;
        *reinterpret_cast<float4*>(&Ws[rr][c4]) =
            *reinterpret_cast<const float4*>(W + (size_t)(kc + rr) * HF + c4);
      }
    }
    __syncthreads();
#pragma unroll
    for (int k = 0; k < 32; ++k) {
      float2 p0 = *reinterpret_cast<const float2*>(&As[k][ty * 4]);
      float2 p1 = *reinterpret_cast<const float2*>(&As[k][ty * 4 + 2]);
      float4 w0 = *reinterpret_cast<const float4*>(&Ws[k][tx * 4]);
      float4 w1 = *reinterpret_cast<const float4*>(&Ws[k][tx * 4 + 64]);
      float av[4] = {p0.x, p0.y, p1.x, p1.y};
      float wv[8] = {w0.x, w0.y, w0.z, w0.w, w1.x, w1.y, w1.z, w1.w};
#pragma unroll
      for (int i = 0; i < 4; i++)
#pragma unroll
        for (int j = 0; j < 8; j++) acc[i][j] = fmaf(av[i], wv[j], acc[i][j]);
    }
    __syncthreads();
  }

  float4 bb0 = *reinterpret_cast<const float4*>(bias + tx * 4);
  float4 bb1 = *reinterpret_cast<const float4*>(bias + tx * 4 + 64);
  float bb[8] = {bb0.x, bb0.y, bb0.z, bb0.w, bb1.x, bb1.y, bb1.z, bb1.w};
#pragma unroll
  for (int i = 0; i < 4; ++i) {
    int node = n0 + ty * 4 + i;
    if (node < n) {
      float o[8];
#pragma unroll
      for (int j = 0; j < 8; j++) o[j] = leaky(acc[i][j] + bb[j]);
      *reinterpret_cast<float4*>(out + (size_t)node * HF + tx * 4) = make_float4(o[0], o[1], o[2], o[3]);
      *reinterpret_cast<float4*>(out + (size_t)node * HF + tx * 4 + 64) = make_float4(o[4], o[5], o[6], o[7]);
    }
  }
}

// ---------------- head ----------------

__global__ __launch_bounds__(256) void k_head(const float* __restrict__ h, const float* __restrict__ fcW,
                                              const float* __restrict__ fcb, float* __restrict__ out, int n) {
  int gw = (blockIdx.x * 256 + threadIdx.x) >> 6;
  int lane = threadIdx.x & 63;
  int node = gw * 8 + (lane >> 3);
  int part = lane & 7;
  float a0 = 0.f, a1 = 0.f, a2 = 0.f, a3 = 0.f;
  if (node < n) {
    const float* hp = h + (size_t)node * HF + part * 16;
#pragma unroll
    for (int i = 0; i < 16; i++) {
      float xv = hp[i];
      float4 wk = *reinterpret_cast<const float4*>(fcW + (part * 16 + i) * 4);
      a0 = fmaf(xv, wk.x, a0);
      a1 = fmaf(xv, wk.y, a1);
      a2 = fmaf(xv, wk.z, a2);
      a3 = fmaf(xv, wk.w, a3);
    }
  }
#pragma unroll
  for (int m = 1; m < 8; m <<= 1) {
    a0 += __shfl_xor(a0, m, 64);
    a1 += __shfl_xor(a1, m, 64);
    a2 += __shfl_xor(a2, m, 64);
    a3 += __shfl_xor(a3, m, 64);
  }
  if (part == 0 && node < n) {
    float4 o = make_float4(a0 + fcb[0], a1 + fcb[1], a2 + fcb[2], a3 + fcb[3]);
    *reinterpret_cast<float4*>(out + (size_t)node * 4) = o;
  }
}

// ---------------- launch ----------------

extern "C" void kernel_launch(void* const* d_in, const int* in_sizes, int n_in,
                              void* d_out, int out_size, void* d_ws, size_t ws_size,
                              hipStream_t stream) {
  const float* x = (const float*)d_in[0];
  const float* ew = (const float*)d_in[1];
  const int* src = (const int*)d_in[2];
  const int* dst = (const int*)d_in[3];
  const float* W1 = (const float*)d_in[4];
  const float* b1 = (const float*)d_in[5];
  const float* Wst = (const float*)d_in[6];
  const float* bst = (const float*)d_in[7];
  const float* fcW = (const float*)d_in[8];
  const float* fcb = (const float*)d_in[9];
  float* out = (float*)d_out;

  const int n = NN, e = NE;
  char* w = (char*)d_ws;
  size_t off = 0;
  auto alloc = [&](size_t bytes) {
    void* p = w + off;
    off += (bytes + 511) & ~(size_t)511;
    return p;
  };
  int* dout = (int*)alloc((size_t)n * 4);
  int* din = (int*)alloc((size_t)n * 4);
  float* iso = (float*)alloc((size_t)n * 4);
  float* isi = (float*)alloc((size_t)n * 4);
  int* rp = (int*)alloc((size_t)(n + 1) * 4);
  int* cursor = (int*)alloc((size_t)n * 4);
  int* bsum = (int*)alloc((size_t)NB_SCAN * 4);
  int* boff = (int*)alloc((size_t)NB_SCAN * 4);
  int2* cv = (int2*)alloc((size_t)e * 8);
  float* h = (float*)alloc((size_t)n * HF * 4);
  float* agg = (float*)alloc((size_t)n * HF * 4);
  float* agg16 = agg;  // reuse

  hipMemsetAsync(dout, 0, (size_t)n * 4, stream);
  hipMemsetAsync(din, 0, (size_t)n * 4, stream);
  hipMemsetAsync(cursor, 0, (size_t)n * 4, stream);

  const int eh = 800000;  // e/2, multiple of 4
  k_deg1<<<idiv(eh, 1024), 256, 0, stream>>>(src, dout, 0, eh);
  k_deg1<<<idiv(e - eh, 1024), 256, 0, stream>>>(src, dout, eh, e);
  k_deg1<<<idiv(eh, 1024), 256, 0, stream>>>(dst, din, 0, eh);
  k_deg1<<<idiv(e - eh, 1024), 256, 0, stream>>>(dst, din, eh, e);
  k_norms<<<idiv(n, 256), 256, 0, stream>>>(dout, din, iso, isi, n);

  k_scan_part<<<NB_SCAN, 1024, 0, stream>>>(din, bsum, n);
  k_scan_small<<<1, 128, 0, stream>>>(bsum, boff, rp, n, NB_SCAN);
  k_scan_final<<<NB_SCAN, 1024, 0, stream>>>(din, boff, rp, n);

  k_build<<<idiv(eh, 256), 256, 0, stream>>>(src, dst, ew, iso, isi, rp, cursor, cv, 0, eh);
  k_build<<<idiv(e - eh, 256), 256, 0, stream>>>(src, dst, ew, iso, isi, rp, cursor, cv, eh, e);

  k_spmm16<<<idiv(n * INF, 256), 256, 0, stream>>>(x, rp, cv, agg16, n);
  k_gemm16<<<idiv(n * HF, 256), 256, 0, stream>>>(agg16, W1, b1, h, n);

  // 3-way node-range split of spmm (telemetry: keeps k_gemm in rocprof top-5)
  const int s1 = 33336, s2 = 66672;  // multiples of 4
  for (int l = 0; l < NLAYERS; ++l) {
    k_spmm<<<idiv(s1 - 0, 4), 256, 0, stream>>>(h, rp, cv, agg, 0, s1);
    k_spmm<<<idiv(s2 - s1, 4), 256, 0, stream>>>(h, rp, cv, agg, s1, s2);
    k_spmm<<<idiv(n - s2, 4), 256, 0, stream>>>(h, rp, cv, agg, s2, n);
    k_gemm<<<idiv(n, 64), 256, 0, stream>>>(agg, Wst + (size_t)l * HF * HF, bst + (size_t)l * HF, h, n);
  }
  k_head<<<idiv(n * 8, 256), 256, 0, stream>>>(h, fcW, fcb, out, n);
}